// Round 9
// baseline (167.878 us; speedup 1.0000x reference)
//
#include <hip/hip_runtime.h>

#define TT 512
#define BIGS 1.4426950408889634e10f   // BIG(1e10) * log2(e), scaled domain
#define LOG2E 1.4426950408889634f
#define M2L  (-2.0f * 1.4426950408889634f)
#define LN2F 0.69314718055994531f
#define P_SS 16                       // ticks per superstep (barrier period)
#define G_LAG 96                      // band lag (deferred-seam margins, see proof)
#define N_SS 54                       // band3: tb=16s-288 in [0,575] -> s<=53
#define RSTR 130                      // ring row stride (words); 128 slots + pad

typedef _Float16 h2 __attribute__((ext_vector_type(2)));

__device__ __forceinline__ unsigned pk(float a, float b) {
    h2 v; v.x = (_Float16)a; v.y = (_Float16)b;
    return __builtin_bit_cast(unsigned, v);
}

#if __has_builtin(__builtin_amdgcn_fdot2)
#define FDOT2(a, b, c) __builtin_amdgcn_fdot2(__builtin_bit_cast(h2, (a)), \
                                              __builtin_bit_cast(h2, (b)), (c), false)
#else
__device__ __forceinline__ float fdot2_sw(unsigned a, unsigned b, float c) {
    h2 ha = __builtin_bit_cast(h2, a), hb = __builtin_bit_cast(h2, b);
    return c + (float)ha.x * (float)hb.x + (float)ha.y * (float)hb.y;
}
#define FDOT2(a, b, c) fdot2_sw((a), (b), (c))
#endif

#if __has_builtin(__builtin_amdgcn_exp2f)
#define EXP2F(x) __builtin_amdgcn_exp2f(x)
#else
#define EXP2F(x) exp2f(x)
#endif

// permuted Z index, pure bitops (valid for any int j; wraps out-of-range j
// onto some valid row -- garbage rows only feed masked ticks)
#define ZROW(jv) (((((jv) & 1)) << 8) | ((((jv) >> 1)) & 255))

// lane-shift-up-by-1 via DPP wave_shr:1 (VALU) on the loop-carried path.
// Lane 0 takes `old` = seam value. Verified r13-r18.
__device__ __forceinline__ float dppshr1(float x, float old) {
#if __has_builtin(__builtin_amdgcn_update_dpp)
    return __builtin_bit_cast(float,
        __builtin_amdgcn_update_dpp(__builtin_bit_cast(int, old),
                                    __builtin_bit_cast(int, x),
                                    0x138 /*wave_shr:1*/, 0xF, 0xF, false));
#else
    const float v = __shfl_up(x, 1);
    return ((threadIdx.x & 63) == 0) ? old : v;
#endif
}

// ---------------------------------------------------------------------------
// Round 19 = r18 (112.8us) + S-LAGGED TICK: exp2 off the loop-carried chain.
// Accounting from r18: SIMD issue ~2530cy/ss vs wall 5300cy/ss; producers
// exhaust their work early; the residual DP-only stall is exp latency on the
// in-order chain (S-tree fma waits on exp2; 2 clusters/tick).
// Fix: software-pipeline the S-recurrence ONE TICK behind K:
//   slot tau: K-chain(tau) [pure fmin/add, ~20cy chain] -> issue 6 exps(tau)
//   into ping-pong regs E[tau&1] -> S-tree(tau-1) consuming E[(tau-1)&1]
//   (issued a full slot earlier -> always ready) -> deferred seam write
//   (K1_d captured at slot start keeps the (K,S) pair tick-consistent)
//   -> DPPs (bnK for tick tau+1, bnS = unS(tau) consumed next slot).
// Legality: softmin result is invariant to the reference m (it cancels), so
// mixed renorm scales across pairs stay legal (same argument as verified
// rounds); renorm applies e to the CURRENT (RpK,RpS) register pair -> both
// K- and S-lineages inherit it consistently. Masks: okS(slot tau) =
// okK(tick tau-1) (pure index function, no carried flag). Tail: slot 575
// (K all-masked) flushes tick 574's S. Activation: S-tree(-1) auto-masked;
// bnS/poS_s/sprevS_d seeded so lane 0's unS(0)=seam.y.
// Seam write moves 1 tick later -> G_LAG 80->96 (write c+64+96b, read
// c+95+96b: 31-tick gap always spans a barrier). Ring pacing T=s-6bd+2
// (1-ss barrier-ordered margin; overwrite margin 6 ss). +48 ticks (+6%)
// traded for the chain cut. Producers byte-identical to r18.
// ---------------------------------------------------------------------------
__global__ __launch_bounds__(768, 1) void k_fused(const float* __restrict__ X,
                                                  const float* __restrict__ Z,
                                                  const float* __restrict__ w,
                                                  float* __restrict__ out) {
    const int tt = threadIdx.x;
    const int t  = tt & 63;          // lane
    const int wv = tt >> 6;          // wave 0..11
    const int bd = wv & 3;           // band this wave serves
    const int hf = (wv >= 8) ? 1 : 0;// producer half (wv>=4 only)
    const int n  = blockIdx.x;       // sample

    __shared__ uint4    ZA[2][512];  // Z rows fp16-packed, permuted idx
    __shared__ float    Zs2p[512];   // LOG2E*|z|^2 at permuted idx
    __shared__ float2   seam[4][64]; // seam rings (K, sm); band0 = border
    __shared__ unsigned ring[4][64][RSTR];  // fp16x2 dd pairs, slot = col&127

    // ---- stage Z into LDS: threads 0..511 handle one row each ----
    if (tt < 512) {
        const int r = tt;
        const float4* zp = (const float4*)(Z + (size_t)r * 16);
        const float4 a0 = zp[0], a1 = zp[1], a2 = zp[2], a3 = zp[3];
        float sv = 0.0f;
        sv = fmaf(a0.x, a0.x, sv); sv = fmaf(a0.y, a0.y, sv);
        sv = fmaf(a0.z, a0.z, sv); sv = fmaf(a0.w, a0.w, sv);
        sv = fmaf(a1.x, a1.x, sv); sv = fmaf(a1.y, a1.y, sv);
        sv = fmaf(a1.z, a1.z, sv); sv = fmaf(a1.w, a1.w, sv);
        sv = fmaf(a2.x, a2.x, sv); sv = fmaf(a2.y, a2.y, sv);
        sv = fmaf(a2.z, a2.z, sv); sv = fmaf(a2.w, a2.w, sv);
        sv = fmaf(a3.x, a3.x, sv); sv = fmaf(a3.y, a3.y, sv);
        sv = fmaf(a3.z, a3.z, sv); sv = fmaf(a3.w, a3.w, sv);
        const int idx = ((r & 1) << 8) | (r >> 1);
        ZA[0][idx] = make_uint4(pk(a0.x, a0.y), pk(a0.z, a0.w),
                                pk(a1.x, a1.y), pk(a1.z, a1.w));
        ZA[1][idx] = make_uint4(pk(a2.x, a2.y), pk(a2.z, a2.w),
                                pk(a3.x, a3.y), pk(a3.z, a3.w));
        Zs2p[idx] = LOG2E * sv;
    }
    // seam rings -> (BIGS, 1): matrix border; band-0 ring never written.
    if (tt < 256) ((float2*)&seam[0][0])[tt] = make_float2(BIGS, 1.0f);

    // ---- X rows for band bd, lane t (rows i0, i0+1) -> registers ----
    const int i0 = 128 * bd + 2 * t;
    unsigned Xu[2][8];
    float    xs2[2];
    const float* xp = X + ((size_t)n * TT + i0) * 16;
#pragma unroll
    for (int q = 0; q < 2; ++q) {
        const float4* xr = (const float4*)(xp + q * 16);
        const float4 a0 = xr[0], a1 = xr[1], a2 = xr[2], a3 = xr[3];
        float sv = 0.0f;
        sv = fmaf(a0.x, a0.x, sv); sv = fmaf(a0.y, a0.y, sv);
        sv = fmaf(a0.z, a0.z, sv); sv = fmaf(a0.w, a0.w, sv);
        sv = fmaf(a1.x, a1.x, sv); sv = fmaf(a1.y, a1.y, sv);
        sv = fmaf(a1.z, a1.z, sv); sv = fmaf(a1.w, a1.w, sv);
        sv = fmaf(a2.x, a2.x, sv); sv = fmaf(a2.y, a2.y, sv);
        sv = fmaf(a2.z, a2.z, sv); sv = fmaf(a2.w, a2.w, sv);
        sv = fmaf(a3.x, a3.x, sv); sv = fmaf(a3.y, a3.y, sv);
        sv = fmaf(a3.z, a3.z, sv); sv = fmaf(a3.w, a3.w, sv);
        xs2[q] = LOG2E * sv;
        Xu[q][0] = pk(a0.x, a0.y); Xu[q][1] = pk(a0.z, a0.w);
        Xu[q][2] = pk(a1.x, a1.y); Xu[q][3] = pk(a1.z, a1.w);
        Xu[q][4] = pk(a2.x, a2.y); Xu[q][5] = pk(a2.z, a2.w);
        Xu[q][6] = pk(a3.x, a3.y); Xu[q][7] = pk(a3.z, a3.w);
    }
    const float wgt = w[n];
    const float2* rKS = &seam[bd][0];
    unsigned* const rg = &ring[bd][t][0];
    __syncthreads();

    // producer: fp16-packed dd pair for 8 cols of tile Tv (half hf)
#define PRODUCE(Tv)                                                           \
    {                                                                         \
        const int base_ = ((Tv) << 4) + (hf << 3);                            \
        const int wb_ = base_ & 127;                                          \
        _Pragma("unroll 4")                                                   \
        for (int cc = 0; cc < 8; ++cc) {                                      \
            const int zr = ZROW(base_ + cc);       /* wave-uniform */         \
            const uint4 z0 = ZA[0][zr], z1 = ZA[1][zr];                       \
            const float zz = Zs2p[zr];                                        \
            float a0 = 0.0f, b0 = 0.0f, a1 = 0.0f, b1 = 0.0f;                 \
            a0 = FDOT2(z0.x, Xu[0][0], a0); a0 = FDOT2(z0.y, Xu[0][1], a0);   \
            a0 = FDOT2(z0.z, Xu[0][2], a0); a0 = FDOT2(z0.w, Xu[0][3], a0);   \
            b0 = FDOT2(z1.x, Xu[0][4], b0); b0 = FDOT2(z1.y, Xu[0][5], b0);   \
            b0 = FDOT2(z1.z, Xu[0][6], b0); b0 = FDOT2(z1.w, Xu[0][7], b0);   \
            a1 = FDOT2(z0.x, Xu[1][0], a1); a1 = FDOT2(z0.y, Xu[1][1], a1);   \
            a1 = FDOT2(z0.z, Xu[1][2], a1); a1 = FDOT2(z0.w, Xu[1][3], a1);   \
            b1 = FDOT2(z1.x, Xu[1][4], b1); b1 = FDOT2(z1.y, Xu[1][5], b1);   \
            b1 = FDOT2(z1.z, Xu[1][6], b1); b1 = FDOT2(z1.w, Xu[1][7], b1);   \
            const float dd0 = fmaf(M2L, a0 + b0, xs2[0] + zz);                \
            const float dd1 = fmaf(M2L, a1 + b1, xs2[1] + zz);                \
            rg[wb_ + cc] = pk(dd0, dd1);                                      \
        }                                                                     \
    }

    // pre-loop: band 0's tiles 0,1 (consumed at s=0) behind one barrier
    if (wv >= 4 && bd == 0) { PRODUCE(0) PRODUCE(1) }
    __syncthreads();

    // ---- DP state (producers carry these dead) ----
    float RpK[2], RpS[2], poK, poS_s, bnK, bnS;
    float E[2][6];                   // exp ping-pong (written slot tl, read tl+1)
    float sprevS_d;                  // seam .y delayed one slot (for dppS)
    unsigned rv[2];                  // ring prefetch slots (parity of tl)
    RpK[0] = RpK[1] = BIGS; RpS[0] = RpS[1] = 1.0f;
    poK = BIGS; poS_s = 1.0f; bnK = BIGS; bnS = 1.0f;
    sprevS_d = 1.0f;
    rv[0] = rv[1] = 0u;
#pragma unroll
    for (int e = 0; e < 6; ++e) { E[0][e] = 1.0f; E[1][e] = 1.0f; }

// q must equal (tl)&1 at each expansion (tb is even). ALLOK: compile-time
// "every lane valid for both tick tl and deferred tick tl-1".
#define LTICK(q, tl, ALLOK)                                                   \
    {                                                                         \
        const float K1_d = RpK[1];          /* K1(tl-1) for deferred seam */  \
        const float2 sprev = rKS[((tl) + 1) & 63];                            \
        const h2 dh = __builtin_bit_cast(h2, rv[q]);                          \
        rv[q] = rg[((unsigned)((tl) + 2 - t)) & 127];  /* for tick tl+2 */    \
        const float dd0 = (float)dh.x, dd1 = (float)dh.y;                     \
        /* ---- K-chain, tick tl (no exp on the carried path) ---- */         \
        const float unK = bnK;                                                \
        const float pK  = poK;                                                \
        const float l0K = RpK[0], l1K = RpK[1];                               \
        const float m0 = fminf(fminf(unK, l0K), pK);                          \
        const float K0 = dd0 + m0;                                            \
        const float m1 = fminf(fminf(K0, l1K), l0K);                          \
        const float K1 = dd1 + m1;                                            \
        const bool okK = (ALLOK) ? true                                       \
                       : ((((tl) - t) >= 0) && (((tl) - t) < 512));           \
        RpK[0] = okK ? K0 : RpK[0];                                           \
        RpK[1] = okK ? K1 : RpK[1];                                           \
        poK = unK;                                                            \
        /* ---- exps for tick tl -> E[q], consumed NEXT slot ---- */          \
        E[q][0] = EXP2F(m0 - unK);                                            \
        E[q][1] = EXP2F(m0 - l0K);                                            \
        E[q][2] = EXP2F(m0 - pK);                                             \
        E[q][3] = EXP2F(m1 - K0);                                             \
        E[q][4] = EXP2F(m1 - l1K);                                            \
        E[q][5] = EXP2F(m1 - l0K);                                            \
        /* ---- deferred S-tree, tick tl-1 (E[q^1] issued last slot) ---- */  \
        const bool okS = (ALLOK) ? true                                       \
                       : ((((tl) - 1 - t) >= 0) && (((tl) - 1 - t) < 512));   \
        const float s0 = E[(q) ^ 1][0] * bnS + E[(q) ^ 1][1] * RpS[0]         \
                       + E[(q) ^ 1][2] * poS_s;                               \
        const float s1 = E[(q) ^ 1][3] * s0 + E[(q) ^ 1][4] * RpS[1]          \
                       + E[(q) ^ 1][5] * RpS[0];                              \
        RpS[0] = okS ? s0 : RpS[0];                                           \
        RpS[1] = okS ? s1 : RpS[1];                                           \
        if (okS && bd < 3 && t == 63) {   /* seam for tick tl-1; idx (tl)&63 */\
            seam[bd + 1][(tl) & 63] = make_float2(K1_d, RpS[1]);              \
        }                                                                     \
        poS_s = bnS;                        /* unS(tl-1) -> poS(tl) */        \
        /* ---- boundary DPPs ---- */                                         \
        bnK = dppshr1(RpK[1], sprev.x);     /* un K for tick tl+1 */          \
        bnS = dppshr1(RpS[1], sprevS_d);    /* un S for tick tl   */          \
        sprevS_d = sprev.y;                                                   \
    }

#define RENORM                                                                \
    {                                                                         \
        _Pragma("unroll")                                                     \
        for (int q = 0; q < 2; ++q) {                                         \
            const int e = (int)(__float_as_uint(RpS[q]) >> 23) - 127;         \
            RpS[q] = __uint_as_float(__float_as_uint(RpS[q])                  \
                                     - ((unsigned)e << 23));                  \
            RpK[q] -= (float)e;                                               \
        }                                                                     \
    }

#define SS_BODY(A)                                                            \
    LTICK(0, tb + 0, A)  LTICK(1, tb + 1, A)  LTICK(0, tb + 2, A)             \
    LTICK(1, tb + 3, A)  LTICK(0, tb + 4, A)  LTICK(1, tb + 5, A)             \
    LTICK(0, tb + 6, A)  LTICK(1, tb + 7, A)                                  \
    RENORM                                                                    \
    LTICK(0, tb + 8, A)  LTICK(1, tb + 9, A)  LTICK(0, tb + 10, A)            \
    LTICK(1, tb + 11, A) LTICK(0, tb + 12, A) LTICK(1, tb + 13, A)            \
    LTICK(0, tb + 14, A) LTICK(1, tb + 15, A)                                 \
    RENORM

#pragma unroll 1
    for (int s = 0; s < N_SS; ++s) {
        if (wv >= 4) {
            // -------- producer wave: 8 cols of one tile, 2 ss ahead --------
            const int T = s - 6 * bd + 2;
            if (T >= 0 && T <= 31) PRODUCE(T)
        } else {
            // -------- DP wave: 16 slots of band bd --------
            const int tb = P_SS * s - G_LAG * bd;
            if (tb >= 64 && tb <= 496) {
                // interior: ticks tb-1..tb+15 all-valid, masks folded away
                __builtin_amdgcn_s_setprio(1);
                SS_BODY(1)
                __builtin_amdgcn_s_setprio(0);
            } else if (tb >= 0 && tb <= 574) {
                if (tb == 0) {
                    // activation: K state, boundary, S-lag state, ring prefetch
                    RpK[0] = RpK[1] = BIGS; RpS[0] = RpS[1] = 1.0f;
                    poK = (bd == 0 && t == 0) ? 0.0f : BIGS;
                    poS_s = 1.0f;
                    const float2 r0 = rKS[0];
                    bnK = r0.x;          // unK(0): lane0 real, rest masked
                    bnS = 1.0f;          // slot0's poS_s := bnS must be 1
                    sprevS_d = r0.y;     // slot0's dppS old -> lane0 unS(0)
                    rv[0] = rg[((unsigned)(0 - t)) & 127];   // col 0-t (tick 0)
                    rv[1] = rg[((unsigned)(1 - t)) & 127];   // col 1-t (tick 1)
                }
                __builtin_amdgcn_s_setprio(1);
                SS_BODY(0)
                __builtin_amdgcn_s_setprio(0);
            }
        }
        __syncthreads();
    }
#undef LTICK
#undef RENORM
#undef SS_BODY
#undef PRODUCE

    // band 3, lane 63: K1(574) retained through masked slot 575; s1(574)
    // flushed at slot 575; RENORM kept the pair consistent.
    if (wv == 3 && t == 63) {
        atomicAdd(out, wgt * (RpK[1] - log2f(RpS[1])) * LN2F);
    }
}

__global__ void k_zero(float* out) {
    if (threadIdx.x == 0) out[0] = 0.0f;
}

extern "C" void kernel_launch(void* const* d_in, const int* in_sizes, int n_in,
                              void* d_out, int out_size, void* d_ws, size_t ws_size,
                              hipStream_t stream) {
    const float* X = (const float*)d_in[0];   // (64, 512, 16) f32
    const float* w = (const float*)d_in[1];   // (64,) f32
    const float* Z = (const float*)d_in[2];   // (512, 16) f32
    float* out = (float*)d_out;               // scalar f32

    hipLaunchKernelGGL(k_zero, dim3(1), dim3(64), 0, stream, out);
    hipLaunchKernelGGL(k_fused, dim3(64), dim3(768), 0, stream, X, Z, w, out);
}

// Round 10
// 165.077 us; speedup vs baseline: 1.0170x; 1.0170x over previous
//
#include <hip/hip_runtime.h>

#define TT 512
#define BIGS 1.4426950408889634e10f   // BIG(1e10) * log2(e), scaled domain
#define LOG2E 1.4426950408889634f
#define M2L  (-2.0f * 1.4426950408889634f)
#define LN2F 0.69314718055994531f
#define RSTR 130                      // ring row stride (words); 128 slots + pad

typedef _Float16 h2 __attribute__((ext_vector_type(2)));

__device__ __forceinline__ unsigned pk(float a, float b) {
    h2 v; v.x = (_Float16)a; v.y = (_Float16)b;
    return __builtin_bit_cast(unsigned, v);
}

#if __has_builtin(__builtin_amdgcn_fdot2)
#define FDOT2(a, b, c) __builtin_amdgcn_fdot2(__builtin_bit_cast(h2, (a)), \
                                              __builtin_bit_cast(h2, (b)), (c), false)
#else
__device__ __forceinline__ float fdot2_sw(unsigned a, unsigned b, float c) {
    h2 ha = __builtin_bit_cast(h2, a), hb = __builtin_bit_cast(h2, b);
    return c + (float)ha.x * (float)hb.x + (float)ha.y * (float)hb.y;
}
#define FDOT2(a, b, c) fdot2_sw((a), (b), (c))
#endif

#if __has_builtin(__builtin_amdgcn_exp2f)
#define EXP2F(x) __builtin_amdgcn_exp2f(x)
#else
#define EXP2F(x) exp2f(x)
#endif

// permuted Z index, pure bitops (valid for any int j; wraps out-of-range j
// onto some valid row -- garbage rows only feed masked ticks)
#define ZROW(jv) (((((jv) & 1)) << 8) | ((((jv) >> 1)) & 255))

// lane-shift-up-by-1 via DPP wave_shr:1 (VALU) on the loop-carried path.
// Lane 0 takes `old` = seam value. Verified r13-r19.
__device__ __forceinline__ float dppshr1(float x, float old) {
#if __has_builtin(__builtin_amdgcn_update_dpp)
    return __builtin_bit_cast(float,
        __builtin_amdgcn_update_dpp(__builtin_bit_cast(int, old),
                                    __builtin_bit_cast(int, x),
                                    0x138 /*wave_shr:1*/, 0xF, 0xF, false));
#else
    const float v = __shfl_up(x, 1);
    return ((threadIdx.x & 63) == 0) ? old : v;
#endif
}

// wave-uniform spin-wait on an LDS progress counter (s_sleep between polls)
__device__ __forceinline__ void waitge(const volatile int* p, int v) {
    while (*p < v) __builtin_amdgcn_s_sleep(2);
    asm volatile("" ::: "memory");   // keep data reads below the wait
}
__device__ __forceinline__ void waitge2(const volatile int* p, int v) {
    while (p[0] < v || p[1] < v) __builtin_amdgcn_s_sleep(2);
    asm volatile("" ::: "memory");
}

// ---------------------------------------------------------------------------
// Round 20 = r19 slot math (verified, absmax 0) with __syncthreads REPLACED
// by flag-based pairwise sync -> producers become an ELASTIC fill reservoir.
// Accounting from r19: per SIMD-superstep issue 3360cy vs wall 5030cy; the
// ~1700cy dead time is DP stall after producers exhaust their fixed 1-tile
// quota and barrier-wait. Ring has 8 tiles of capacity -- let producers run
// ahead, gated only by overwrite safety.
// Protocol (all targets on 16-slot publish grid; fences = lgkmcnt(0) before
// each flag write; LDS is physically shared -> fence-then-flag suffices):
//   dpProg[b]     : DP band b's completed local slots (published per batch)
//   prodProg[b][h]: producer (b,h) completed tiles
//   DP batch k waits:  dpProg[b-1] >= min(16k+96, 576)   (seam cols <= 16k+16)
//                      dpProg[b+1] >= 16k-112 (k>=8)     (seam ring overwrite)
//                      prodProg[b][*] >= min(k+2, 32)    (dd tiles <= k+1)
//   producer tile T waits: dpProg[b] >= 16T-48 (T>=4)    (ring overwrite)
// Deadlock-free: each mutual-block implies k <= k-3 (contradiction), checked
// for all three wait pairs. Schedule margins identical to r19's proofs.
// DP slot math, S-lag, renorm, masks, activation: byte-identical to r19.
// ---------------------------------------------------------------------------
__global__ __launch_bounds__(768, 1) void k_fused(const float* __restrict__ X,
                                                  const float* __restrict__ Z,
                                                  const float* __restrict__ w,
                                                  float* __restrict__ out) {
    const int tt = threadIdx.x;
    const int t  = tt & 63;          // lane
    const int wv = tt >> 6;          // wave 0..11
    const int bd = wv & 3;           // band this wave serves
    const int hf = (wv >= 8) ? 1 : 0;// producer half (wv>=4 only)
    const int n  = blockIdx.x;       // sample

    __shared__ uint4    ZA[2][512];  // Z rows fp16-packed, permuted idx
    __shared__ float    Zs2p[512];   // LOG2E*|z|^2 at permuted idx
    __shared__ float2   seam[4][64]; // seam rings (K, sm); band0 = border
    __shared__ unsigned ring[4][64][RSTR];  // fp16x2 dd pairs, slot = col&127
    __shared__ int      dpProg[4];   // DP progress (local slots done)
    __shared__ int      prodProg[4][2];  // producer progress (tiles done)

    // ---- stage Z into LDS: threads 0..511 handle one row each ----
    if (tt < 512) {
        const int r = tt;
        const float4* zp = (const float4*)(Z + (size_t)r * 16);
        const float4 a0 = zp[0], a1 = zp[1], a2 = zp[2], a3 = zp[3];
        float sv = 0.0f;
        sv = fmaf(a0.x, a0.x, sv); sv = fmaf(a0.y, a0.y, sv);
        sv = fmaf(a0.z, a0.z, sv); sv = fmaf(a0.w, a0.w, sv);
        sv = fmaf(a1.x, a1.x, sv); sv = fmaf(a1.y, a1.y, sv);
        sv = fmaf(a1.z, a1.z, sv); sv = fmaf(a1.w, a1.w, sv);
        sv = fmaf(a2.x, a2.x, sv); sv = fmaf(a2.y, a2.y, sv);
        sv = fmaf(a2.z, a2.z, sv); sv = fmaf(a2.w, a2.w, sv);
        sv = fmaf(a3.x, a3.x, sv); sv = fmaf(a3.y, a3.y, sv);
        sv = fmaf(a3.z, a3.z, sv); sv = fmaf(a3.w, a3.w, sv);
        const int idx = ((r & 1) << 8) | (r >> 1);
        ZA[0][idx] = make_uint4(pk(a0.x, a0.y), pk(a0.z, a0.w),
                                pk(a1.x, a1.y), pk(a1.z, a1.w));
        ZA[1][idx] = make_uint4(pk(a2.x, a2.y), pk(a2.z, a2.w),
                                pk(a3.x, a3.y), pk(a3.z, a3.w));
        Zs2p[idx] = LOG2E * sv;
    }
    // seam rings -> (BIGS, 1): matrix border; band-0 ring never written.
    if (tt < 256) ((float2*)&seam[0][0])[tt] = make_float2(BIGS, 1.0f);
    // progress flags
    if (tt < 4) dpProg[tt] = 0;
    if (tt < 8) (&prodProg[0][0])[tt] = 0;

    // ---- X rows for band bd, lane t (rows i0, i0+1) -> registers ----
    const int i0 = 128 * bd + 2 * t;
    unsigned Xu[2][8];
    float    xs2[2];
    const float* xp = X + ((size_t)n * TT + i0) * 16;
#pragma unroll
    for (int q = 0; q < 2; ++q) {
        const float4* xr = (const float4*)(xp + q * 16);
        const float4 a0 = xr[0], a1 = xr[1], a2 = xr[2], a3 = xr[3];
        float sv = 0.0f;
        sv = fmaf(a0.x, a0.x, sv); sv = fmaf(a0.y, a0.y, sv);
        sv = fmaf(a0.z, a0.z, sv); sv = fmaf(a0.w, a0.w, sv);
        sv = fmaf(a1.x, a1.x, sv); sv = fmaf(a1.y, a1.y, sv);
        sv = fmaf(a1.z, a1.z, sv); sv = fmaf(a1.w, a1.w, sv);
        sv = fmaf(a2.x, a2.x, sv); sv = fmaf(a2.y, a2.y, sv);
        sv = fmaf(a2.z, a2.z, sv); sv = fmaf(a2.w, a2.w, sv);
        sv = fmaf(a3.x, a3.x, sv); sv = fmaf(a3.y, a3.y, sv);
        sv = fmaf(a3.z, a3.z, sv); sv = fmaf(a3.w, a3.w, sv);
        xs2[q] = LOG2E * sv;
        Xu[q][0] = pk(a0.x, a0.y); Xu[q][1] = pk(a0.z, a0.w);
        Xu[q][2] = pk(a1.x, a1.y); Xu[q][3] = pk(a1.z, a1.w);
        Xu[q][4] = pk(a2.x, a2.y); Xu[q][5] = pk(a2.z, a2.w);
        Xu[q][6] = pk(a3.x, a3.y); Xu[q][7] = pk(a3.z, a3.w);
    }
    const float wgt = w[n];
    const float2* rKS = &seam[bd][0];
    unsigned* const rg = &ring[bd][t][0];
    __syncthreads();   // the ONLY barrier: staging + flag init

    // producer: fp16-packed dd pair for 8 cols of tile Tv (half hf)
#define PRODUCE(Tv)                                                           \
    {                                                                         \
        const int base_ = ((Tv) << 4) + (hf << 3);                            \
        const int wb_ = base_ & 127;                                          \
        _Pragma("unroll 4")                                                   \
        for (int cc = 0; cc < 8; ++cc) {                                      \
            const int zr = ZROW(base_ + cc);       /* wave-uniform */         \
            const uint4 z0 = ZA[0][zr], z1 = ZA[1][zr];                       \
            const float zz = Zs2p[zr];                                        \
            float a0 = 0.0f, b0 = 0.0f, a1 = 0.0f, b1 = 0.0f;                 \
            a0 = FDOT2(z0.x, Xu[0][0], a0); a0 = FDOT2(z0.y, Xu[0][1], a0);   \
            a0 = FDOT2(z0.z, Xu[0][2], a0); a0 = FDOT2(z0.w, Xu[0][3], a0);   \
            b0 = FDOT2(z1.x, Xu[0][4], b0); b0 = FDOT2(z1.y, Xu[0][5], b0);   \
            b0 = FDOT2(z1.z, Xu[0][6], b0); b0 = FDOT2(z1.w, Xu[0][7], b0);   \
            a1 = FDOT2(z0.x, Xu[1][0], a1); a1 = FDOT2(z0.y, Xu[1][1], a1);   \
            a1 = FDOT2(z0.z, Xu[1][2], a1); a1 = FDOT2(z0.w, Xu[1][3], a1);   \
            b1 = FDOT2(z1.x, Xu[1][4], b1); b1 = FDOT2(z1.y, Xu[1][5], b1);   \
            b1 = FDOT2(z1.z, Xu[1][6], b1); b1 = FDOT2(z1.w, Xu[1][7], b1);   \
            const float dd0 = fmaf(M2L, a0 + b0, xs2[0] + zz);                \
            const float dd1 = fmaf(M2L, a1 + b1, xs2[1] + zz);                \
            rg[wb_ + cc] = pk(dd0, dd1);                                      \
        }                                                                     \
    }

    // ---- DP state ----
    float RpK[2], RpS[2], poK, poS_s, bnK, bnS;
    float E[2][6];                   // exp ping-pong (written slot tl, read tl+1)
    float sprevS_d;                  // seam .y delayed one slot (for dppS)
    unsigned rv[2];                  // ring prefetch slots (parity of tl)
    RpK[0] = RpK[1] = BIGS; RpS[0] = RpS[1] = 1.0f;
    poK = BIGS; poS_s = 1.0f; bnK = BIGS; bnS = 1.0f;
    sprevS_d = 1.0f;
    rv[0] = rv[1] = 0u;
#pragma unroll
    for (int e = 0; e < 6; ++e) { E[0][e] = 1.0f; E[1][e] = 1.0f; }

// q must equal (tl)&1 at each expansion (tb is even). ALLOK: compile-time
// "every lane valid for both tick tl and deferred tick tl-1".
#define LTICK(q, tl, ALLOK)                                                   \
    {                                                                         \
        const float K1_d = RpK[1];          /* K1(tl-1) for deferred seam */  \
        const float2 sprev = rKS[((tl) + 1) & 63];                            \
        const h2 dh = __builtin_bit_cast(h2, rv[q]);                          \
        rv[q] = rg[((unsigned)((tl) + 2 - t)) & 127];  /* for tick tl+2 */    \
        const float dd0 = (float)dh.x, dd1 = (float)dh.y;                     \
        /* ---- K-chain, tick tl (no exp on the carried path) ---- */         \
        const float unK = bnK;                                                \
        const float pK  = poK;                                                \
        const float l0K = RpK[0], l1K = RpK[1];                               \
        const float m0 = fminf(fminf(unK, l0K), pK);                          \
        const float K0 = dd0 + m0;                                            \
        const float m1 = fminf(fminf(K0, l1K), l0K);                          \
        const float K1 = dd1 + m1;                                            \
        const bool okK = (ALLOK) ? true                                       \
                       : ((((tl) - t) >= 0) && (((tl) - t) < 512));           \
        RpK[0] = okK ? K0 : RpK[0];                                           \
        RpK[1] = okK ? K1 : RpK[1];                                           \
        poK = unK;                                                            \
        /* ---- exps for tick tl -> E[q], consumed NEXT slot ---- */          \
        E[q][0] = EXP2F(m0 - unK);                                            \
        E[q][1] = EXP2F(m0 - l0K);                                            \
        E[q][2] = EXP2F(m0 - pK);                                             \
        E[q][3] = EXP2F(m1 - K0);                                             \
        E[q][4] = EXP2F(m1 - l1K);                                            \
        E[q][5] = EXP2F(m1 - l0K);                                            \
        /* ---- deferred S-tree, tick tl-1 (E[q^1] issued last slot) ---- */  \
        const bool okS = (ALLOK) ? true                                       \
                       : ((((tl) - 1 - t) >= 0) && (((tl) - 1 - t) < 512));   \
        const float s0 = E[(q) ^ 1][0] * bnS + E[(q) ^ 1][1] * RpS[0]         \
                       + E[(q) ^ 1][2] * poS_s;                               \
        const float s1 = E[(q) ^ 1][3] * s0 + E[(q) ^ 1][4] * RpS[1]          \
                       + E[(q) ^ 1][5] * RpS[0];                              \
        RpS[0] = okS ? s0 : RpS[0];                                           \
        RpS[1] = okS ? s1 : RpS[1];                                           \
        if (okS && bd < 3 && t == 63) {   /* seam for tick tl-1; idx (tl)&63 */\
            seam[bd + 1][(tl) & 63] = make_float2(K1_d, RpS[1]);              \
        }                                                                     \
        poS_s = bnS;                        /* unS(tl-1) -> poS(tl) */        \
        /* ---- boundary DPPs ---- */                                         \
        bnK = dppshr1(RpK[1], sprev.x);     /* un K for tick tl+1 */          \
        bnS = dppshr1(RpS[1], sprevS_d);    /* un S for tick tl   */          \
        sprevS_d = sprev.y;                                                   \
    }

#define RENORM                                                                \
    {                                                                         \
        _Pragma("unroll")                                                     \
        for (int q = 0; q < 2; ++q) {                                         \
            const int e = (int)(__float_as_uint(RpS[q]) >> 23) - 127;         \
            RpS[q] = __uint_as_float(__float_as_uint(RpS[q])                  \
                                     - ((unsigned)e << 23));                  \
            RpK[q] -= (float)e;                                               \
        }                                                                     \
    }

#define SS_BODY(A)                                                            \
    LTICK(0, tb + 0, A)  LTICK(1, tb + 1, A)  LTICK(0, tb + 2, A)             \
    LTICK(1, tb + 3, A)  LTICK(0, tb + 4, A)  LTICK(1, tb + 5, A)             \
    LTICK(0, tb + 6, A)  LTICK(1, tb + 7, A)                                  \
    RENORM                                                                    \
    LTICK(0, tb + 8, A)  LTICK(1, tb + 9, A)  LTICK(0, tb + 10, A)            \
    LTICK(1, tb + 11, A) LTICK(0, tb + 12, A) LTICK(1, tb + 13, A)            \
    LTICK(0, tb + 14, A) LTICK(1, tb + 15, A)                                 \
    RENORM

    if (wv < 4) {
        // ================= DP wave: 36 batches of 16 slots =================
#pragma unroll 1
        for (int k = 0; k < 36; ++k) {
            const int tb = k << 4;
            if (bd > 0) {
                const int tgt = (tb + 96 < 576) ? tb + 96 : 576;
                waitge(&dpProg[bd - 1], tgt);       // seam availability
            }
            if (bd < 3 && k >= 8) {
                waitge(&dpProg[bd + 1], tb - 112);  // seam-ring overwrite
            }
            {
                const int tw = (k + 2 < 32) ? k + 2 : 32;
                waitge2(&prodProg[bd][0], tw);      // dd tiles <= k+1
            }
            __builtin_amdgcn_s_setprio(1);
            if (k == 0) {
                // activation: K state, boundary, S-lag state, ring prefetch
                RpK[0] = RpK[1] = BIGS; RpS[0] = RpS[1] = 1.0f;
                poK = (bd == 0 && t == 0) ? 0.0f : BIGS;
                poS_s = 1.0f;
                const float2 r0 = rKS[0];
                bnK = r0.x;          // unK(0): lane0 real, rest masked
                bnS = 1.0f;          // slot0's poS_s := bnS must be 1
                sprevS_d = r0.y;     // slot0's dppS old -> lane0 unS(0)
                rv[0] = rg[((unsigned)(0 - t)) & 127];   // col 0-t (tick 0)
                rv[1] = rg[((unsigned)(1 - t)) & 127];   // col 1-t (tick 1)
                SS_BODY(0)
            } else if (k >= 4 && k <= 31) {
                SS_BODY(1)
            } else {
                SS_BODY(0)
            }
            __builtin_amdgcn_s_setprio(0);
            asm volatile("s_waitcnt lgkmcnt(0)" ::: "memory");  // drain seam
            if (t == 0) *(volatile int*)&dpProg[bd] = tb + 16;
        }
    } else {
        // ================= producer wave: 32 tiles, free-running ===========
#pragma unroll 1
        for (int T = 0; T < 32; ++T) {
            if (T >= 4) waitge(&dpProg[bd], (T << 4) - 48);  // ring overwrite
            PRODUCE(T)
            asm volatile("s_waitcnt lgkmcnt(0)" ::: "memory");
            if (t == 0) *(volatile int*)&prodProg[bd][hf] = T + 1;
        }
    }
#undef LTICK
#undef RENORM
#undef SS_BODY
#undef PRODUCE

    // band 3, lane 63: K1(574) retained through masked slot 575; s1(574)
    // flushed at slot 575; RENORM kept the pair consistent.
    if (wv == 3 && t == 63) {
        atomicAdd(out, wgt * (RpK[1] - log2f(RpS[1])) * LN2F);
    }
}

__global__ void k_zero(float* out) {
    if (threadIdx.x == 0) out[0] = 0.0f;
}

extern "C" void kernel_launch(void* const* d_in, const int* in_sizes, int n_in,
                              void* d_out, int out_size, void* d_ws, size_t ws_size,
                              hipStream_t stream) {
    const float* X = (const float*)d_in[0];   // (64, 512, 16) f32
    const float* w = (const float*)d_in[1];   // (64,) f32
    const float* Z = (const float*)d_in[2];   // (512, 16) f32
    float* out = (float*)d_out;               // scalar f32

    hipLaunchKernelGGL(k_zero, dim3(1), dim3(64), 0, stream, out);
    hipLaunchKernelGGL(k_fused, dim3(64), dim3(768), 0, stream, X, Z, w, out);
}

// Round 11
// 164.814 us; speedup vs baseline: 1.0186x; 1.0016x over previous
//
#include <hip/hip_runtime.h>

#define TT 512
#define BIGS 1.4426950408889634e10f   // BIG(1e10) * log2(e), scaled domain
#define LOG2E 1.4426950408889634f
#define M2L  (-2.0f * 1.4426950408889634f)
#define LN2F 0.69314718055994531f
#define RSTR 130                      // ring row stride (words); 128 slots + pad

typedef _Float16 h2 __attribute__((ext_vector_type(2)));

__device__ __forceinline__ unsigned pk(float a, float b) {
    h2 v; v.x = (_Float16)a; v.y = (_Float16)b;
    return __builtin_bit_cast(unsigned, v);
}

#if __has_builtin(__builtin_amdgcn_fdot2)
#define FDOT2(a, b, c) __builtin_amdgcn_fdot2(__builtin_bit_cast(h2, (a)), \
                                              __builtin_bit_cast(h2, (b)), (c), false)
#else
__device__ __forceinline__ float fdot2_sw(unsigned a, unsigned b, float c) {
    h2 ha = __builtin_bit_cast(h2, a), hb = __builtin_bit_cast(h2, b);
    return c + (float)ha.x * (float)hb.x + (float)ha.y * (float)hb.y;
}
#define FDOT2(a, b, c) fdot2_sw((a), (b), (c))
#endif

#if __has_builtin(__builtin_amdgcn_exp2f)
#define EXP2F(x) __builtin_amdgcn_exp2f(x)
#else
#define EXP2F(x) exp2f(x)
#endif

// permuted Z index, pure bitops (valid for any int j; wraps out-of-range j
// onto some valid row -- garbage rows only feed masked ticks)
#define ZROW(jv) (((((jv) & 1)) << 8) | ((((jv) >> 1)) & 255))

// lane-shift-up-by-1 via DPP wave_shr:1 (VALU) on the loop-carried path.
// Lane 0 takes `old` = seam value. Verified r13-r20.
__device__ __forceinline__ float dppshr1(float x, float old) {
#if __has_builtin(__builtin_amdgcn_update_dpp)
    return __builtin_bit_cast(float,
        __builtin_amdgcn_update_dpp(__builtin_bit_cast(int, old),
                                    __builtin_bit_cast(int, x),
                                    0x138 /*wave_shr:1*/, 0xF, 0xF, false));
#else
    const float v = __shfl_up(x, 1);
    return ((threadIdx.x & 63) == 0) ? old : v;
#endif
}

// wave-uniform spin-wait on an LDS progress counter; returns last seen value
// so callers can cache it (flags are monotone -> cached >= target skips the
// ~120cy LDS poll round-trip entirely).
__device__ __forceinline__ int waitge(const volatile int* p, int v) {
    int x = *p;
    while (x < v) { __builtin_amdgcn_s_sleep(2); x = *p; }
    asm volatile("" ::: "memory");   // keep data reads below the wait
    return x;
}
__device__ __forceinline__ int waitge2(const volatile int* p, int v) {
    int a = p[0], b = p[1];
    while (a < v || b < v) { __builtin_amdgcn_s_sleep(2); a = p[0]; b = p[1]; }
    asm volatile("" ::: "memory");
    return (a < b) ? a : b;
}

// ---------------------------------------------------------------------------
// Round 21 = r20 (flag-sync producer/consumer, 112us) + the one remaining
// identified per-slot latency exposure removed:
//  1. SEAM PREFETCH DISTANCE 3 (smv[2] ping-pong, r14's pattern): the r17+
//     in-slot seam read rKS[(tl+1)&63] feeds the DPP `old` at the END of the
//     same slot -> ~120cy ds_read latency exposed EVERY slot (= the ~150cy
//     unexplained slot stall; r18/r19/r20 proved it isn't chain, exps, or
//     fill). Now: sprev = smv[q] (read 2 slots ago); smv[q] = rKS[(tl+3)&63].
//     Margins under the flag protocol (re-proved): batch k reads seam cols
//     <= tb+18, gate dpProg[b-1] >= 16k+96 -> cols <= 16k+32 written
//     (margin 13); overwrite gate dpProg[b+1] >= tb-112 leaves margin 5 at
//     distance-3 reads. Activation seeds smv[0]=rKS[1], smv[1]=rKS[2].
//  2. FLAG-POLL CACHING: waitge returns the seen value; a register cache
//     skips the poll when already satisfied (monotone flags) -- saves up to
//     3 LDS round-trips per batch.
// Everything else (protocol, pacing, S-lag slot math, renorm, masks,
// activation, producers) byte-identical to r20 (absmax 0 verified).
// ---------------------------------------------------------------------------
__global__ __launch_bounds__(768, 1) void k_fused(const float* __restrict__ X,
                                                  const float* __restrict__ Z,
                                                  const float* __restrict__ w,
                                                  float* __restrict__ out) {
    const int tt = threadIdx.x;
    const int t  = tt & 63;          // lane
    const int wv = tt >> 6;          // wave 0..11
    const int bd = wv & 3;           // band this wave serves
    const int hf = (wv >= 8) ? 1 : 0;// producer half (wv>=4 only)
    const int n  = blockIdx.x;       // sample

    __shared__ uint4    ZA[2][512];  // Z rows fp16-packed, permuted idx
    __shared__ float    Zs2p[512];   // LOG2E*|z|^2 at permuted idx
    __shared__ float2   seam[4][64]; // seam rings (K, sm); band0 = border
    __shared__ unsigned ring[4][64][RSTR];  // fp16x2 dd pairs, slot = col&127
    __shared__ int      dpProg[4];   // DP progress (local slots done)
    __shared__ int      prodProg[4][2];  // producer progress (tiles done)

    // ---- stage Z into LDS: threads 0..511 handle one row each ----
    if (tt < 512) {
        const int r = tt;
        const float4* zp = (const float4*)(Z + (size_t)r * 16);
        const float4 a0 = zp[0], a1 = zp[1], a2 = zp[2], a3 = zp[3];
        float sv = 0.0f;
        sv = fmaf(a0.x, a0.x, sv); sv = fmaf(a0.y, a0.y, sv);
        sv = fmaf(a0.z, a0.z, sv); sv = fmaf(a0.w, a0.w, sv);
        sv = fmaf(a1.x, a1.x, sv); sv = fmaf(a1.y, a1.y, sv);
        sv = fmaf(a1.z, a1.z, sv); sv = fmaf(a1.w, a1.w, sv);
        sv = fmaf(a2.x, a2.x, sv); sv = fmaf(a2.y, a2.y, sv);
        sv = fmaf(a2.z, a2.z, sv); sv = fmaf(a2.w, a2.w, sv);
        sv = fmaf(a3.x, a3.x, sv); sv = fmaf(a3.y, a3.y, sv);
        sv = fmaf(a3.z, a3.z, sv); sv = fmaf(a3.w, a3.w, sv);
        const int idx = ((r & 1) << 8) | (r >> 1);
        ZA[0][idx] = make_uint4(pk(a0.x, a0.y), pk(a0.z, a0.w),
                                pk(a1.x, a1.y), pk(a1.z, a1.w));
        ZA[1][idx] = make_uint4(pk(a2.x, a2.y), pk(a2.z, a2.w),
                                pk(a3.x, a3.y), pk(a3.z, a3.w));
        Zs2p[idx] = LOG2E * sv;
    }
    // seam rings -> (BIGS, 1): matrix border; band-0 ring never written.
    if (tt < 256) ((float2*)&seam[0][0])[tt] = make_float2(BIGS, 1.0f);
    // progress flags
    if (tt < 4) dpProg[tt] = 0;
    if (tt < 8) (&prodProg[0][0])[tt] = 0;

    // ---- X rows for band bd, lane t (rows i0, i0+1) -> registers ----
    const int i0 = 128 * bd + 2 * t;
    unsigned Xu[2][8];
    float    xs2[2];
    const float* xp = X + ((size_t)n * TT + i0) * 16;
#pragma unroll
    for (int q = 0; q < 2; ++q) {
        const float4* xr = (const float4*)(xp + q * 16);
        const float4 a0 = xr[0], a1 = xr[1], a2 = xr[2], a3 = xr[3];
        float sv = 0.0f;
        sv = fmaf(a0.x, a0.x, sv); sv = fmaf(a0.y, a0.y, sv);
        sv = fmaf(a0.z, a0.z, sv); sv = fmaf(a0.w, a0.w, sv);
        sv = fmaf(a1.x, a1.x, sv); sv = fmaf(a1.y, a1.y, sv);
        sv = fmaf(a1.z, a1.z, sv); sv = fmaf(a1.w, a1.w, sv);
        sv = fmaf(a2.x, a2.x, sv); sv = fmaf(a2.y, a2.y, sv);
        sv = fmaf(a2.z, a2.z, sv); sv = fmaf(a2.w, a2.w, sv);
        sv = fmaf(a3.x, a3.x, sv); sv = fmaf(a3.y, a3.y, sv);
        sv = fmaf(a3.z, a3.z, sv); sv = fmaf(a3.w, a3.w, sv);
        xs2[q] = LOG2E * sv;
        Xu[q][0] = pk(a0.x, a0.y); Xu[q][1] = pk(a0.z, a0.w);
        Xu[q][2] = pk(a1.x, a1.y); Xu[q][3] = pk(a1.z, a1.w);
        Xu[q][4] = pk(a2.x, a2.y); Xu[q][5] = pk(a2.z, a2.w);
        Xu[q][6] = pk(a3.x, a3.y); Xu[q][7] = pk(a3.z, a3.w);
    }
    const float wgt = w[n];
    const float2* rKS = &seam[bd][0];
    unsigned* const rg = &ring[bd][t][0];
    __syncthreads();   // the ONLY barrier: staging + flag init

    // producer: fp16-packed dd pair for 8 cols of tile Tv (half hf)
#define PRODUCE(Tv)                                                           \
    {                                                                         \
        const int base_ = ((Tv) << 4) + (hf << 3);                            \
        const int wb_ = base_ & 127;                                          \
        _Pragma("unroll 4")                                                   \
        for (int cc = 0; cc < 8; ++cc) {                                      \
            const int zr = ZROW(base_ + cc);       /* wave-uniform */         \
            const uint4 z0 = ZA[0][zr], z1 = ZA[1][zr];                       \
            const float zz = Zs2p[zr];                                        \
            float a0 = 0.0f, b0 = 0.0f, a1 = 0.0f, b1 = 0.0f;                 \
            a0 = FDOT2(z0.x, Xu[0][0], a0); a0 = FDOT2(z0.y, Xu[0][1], a0);   \
            a0 = FDOT2(z0.z, Xu[0][2], a0); a0 = FDOT2(z0.w, Xu[0][3], a0);   \
            b0 = FDOT2(z1.x, Xu[0][4], b0); b0 = FDOT2(z1.y, Xu[0][5], b0);   \
            b0 = FDOT2(z1.z, Xu[0][6], b0); b0 = FDOT2(z1.w, Xu[0][7], b0);   \
            a1 = FDOT2(z0.x, Xu[1][0], a1); a1 = FDOT2(z0.y, Xu[1][1], a1);   \
            a1 = FDOT2(z0.z, Xu[1][2], a1); a1 = FDOT2(z0.w, Xu[1][3], a1);   \
            b1 = FDOT2(z1.x, Xu[1][4], b1); b1 = FDOT2(z1.y, Xu[1][5], b1);   \
            b1 = FDOT2(z1.z, Xu[1][6], b1); b1 = FDOT2(z1.w, Xu[1][7], b1);   \
            const float dd0 = fmaf(M2L, a0 + b0, xs2[0] + zz);                \
            const float dd1 = fmaf(M2L, a1 + b1, xs2[1] + zz);                \
            rg[wb_ + cc] = pk(dd0, dd1);                                      \
        }                                                                     \
    }

    // ---- DP state ----
    float RpK[2], RpS[2], poK, poS_s, bnK, bnS;
    float E[2][6];                   // exp ping-pong (written slot tl, read tl+1)
    float2 smv[2];                   // seam prefetch (distance 3, parity of tl)
    float sprevS_d;                  // seam .y delayed one slot (for dppS)
    unsigned rv[2];                  // ring prefetch slots (parity of tl)
    RpK[0] = RpK[1] = BIGS; RpS[0] = RpS[1] = 1.0f;
    poK = BIGS; poS_s = 1.0f; bnK = BIGS; bnS = 1.0f;
    sprevS_d = 1.0f;
    smv[0] = smv[1] = make_float2(BIGS, 1.0f);
    rv[0] = rv[1] = 0u;
#pragma unroll
    for (int e = 0; e < 6; ++e) { E[0][e] = 1.0f; E[1][e] = 1.0f; }

// q must equal (tl)&1 at each expansion (tb is even). ALLOK: compile-time
// "every lane valid for both tick tl and deferred tick tl-1".
#define LTICK(q, tl, ALLOK)                                                   \
    {                                                                         \
        const float K1_d = RpK[1];          /* K1(tl-1) for deferred seam */  \
        const float2 sprev = smv[q];        /* seam col tl+1 (prefetched) */  \
        smv[q] = rKS[((tl) + 3) & 63];      /* seam col tl+3, for slot tl+2 */\
        const h2 dh = __builtin_bit_cast(h2, rv[q]);                          \
        rv[q] = rg[((unsigned)((tl) + 2 - t)) & 127];  /* for tick tl+2 */    \
        const float dd0 = (float)dh.x, dd1 = (float)dh.y;                     \
        /* ---- K-chain, tick tl (no exp on the carried path) ---- */         \
        const float unK = bnK;                                                \
        const float pK  = poK;                                                \
        const float l0K = RpK[0], l1K = RpK[1];                               \
        const float m0 = fminf(fminf(unK, l0K), pK);                          \
        const float K0 = dd0 + m0;                                            \
        const float m1 = fminf(fminf(K0, l1K), l0K);                          \
        const float K1 = dd1 + m1;                                            \
        const bool okK = (ALLOK) ? true                                       \
                       : ((((tl) - t) >= 0) && (((tl) - t) < 512));           \
        RpK[0] = okK ? K0 : RpK[0];                                           \
        RpK[1] = okK ? K1 : RpK[1];                                           \
        poK = unK;                                                            \
        /* ---- exps for tick tl -> E[q], consumed NEXT slot ---- */          \
        E[q][0] = EXP2F(m0 - unK);                                            \
        E[q][1] = EXP2F(m0 - l0K);                                            \
        E[q][2] = EXP2F(m0 - pK);                                             \
        E[q][3] = EXP2F(m1 - K0);                                             \
        E[q][4] = EXP2F(m1 - l1K);                                            \
        E[q][5] = EXP2F(m1 - l0K);                                            \
        /* ---- deferred S-tree, tick tl-1 (E[q^1] issued last slot) ---- */  \
        const bool okS = (ALLOK) ? true                                       \
                       : ((((tl) - 1 - t) >= 0) && (((tl) - 1 - t) < 512));   \
        const float s0 = E[(q) ^ 1][0] * bnS + E[(q) ^ 1][1] * RpS[0]         \
                       + E[(q) ^ 1][2] * poS_s;                               \
        const float s1 = E[(q) ^ 1][3] * s0 + E[(q) ^ 1][4] * RpS[1]          \
                       + E[(q) ^ 1][5] * RpS[0];                              \
        RpS[0] = okS ? s0 : RpS[0];                                           \
        RpS[1] = okS ? s1 : RpS[1];                                           \
        if (okS && bd < 3 && t == 63) {   /* seam for tick tl-1; idx (tl)&63 */\
            seam[bd + 1][(tl) & 63] = make_float2(K1_d, RpS[1]);              \
        }                                                                     \
        poS_s = bnS;                        /* unS(tl-1) -> poS(tl) */        \
        /* ---- boundary DPPs ---- */                                         \
        bnK = dppshr1(RpK[1], sprev.x);     /* un K for tick tl+1 */          \
        bnS = dppshr1(RpS[1], sprevS_d);    /* un S for tick tl   */          \
        sprevS_d = sprev.y;                                                   \
    }

#define RENORM                                                                \
    {                                                                         \
        _Pragma("unroll")                                                     \
        for (int q = 0; q < 2; ++q) {                                         \
            const int e = (int)(__float_as_uint(RpS[q]) >> 23) - 127;         \
            RpS[q] = __uint_as_float(__float_as_uint(RpS[q])                  \
                                     - ((unsigned)e << 23));                  \
            RpK[q] -= (float)e;                                               \
        }                                                                     \
    }

#define SS_BODY(A)                                                            \
    LTICK(0, tb + 0, A)  LTICK(1, tb + 1, A)  LTICK(0, tb + 2, A)             \
    LTICK(1, tb + 3, A)  LTICK(0, tb + 4, A)  LTICK(1, tb + 5, A)             \
    LTICK(0, tb + 6, A)  LTICK(1, tb + 7, A)                                  \
    RENORM                                                                    \
    LTICK(0, tb + 8, A)  LTICK(1, tb + 9, A)  LTICK(0, tb + 10, A)            \
    LTICK(1, tb + 11, A) LTICK(0, tb + 12, A) LTICK(1, tb + 13, A)            \
    LTICK(0, tb + 14, A) LTICK(1, tb + 15, A)                                 \
    RENORM

    if (wv < 4) {
        // ================= DP wave: 36 batches of 16 slots =================
        int cSeam = 0, cOvw = 0, cProd = 0;   // cached flag values
#pragma unroll 1
        for (int k = 0; k < 36; ++k) {
            const int tb = k << 4;
            if (bd > 0) {
                const int tgt = (tb + 96 < 576) ? tb + 96 : 576;
                if (cSeam < tgt) cSeam = waitge(&dpProg[bd - 1], tgt);
            }
            if (bd < 3 && k >= 8) {
                const int tgt = tb - 112;
                if (cOvw < tgt) cOvw = waitge(&dpProg[bd + 1], tgt);
            }
            {
                const int tw = (k + 2 < 32) ? k + 2 : 32;
                if (cProd < tw) cProd = waitge2(&prodProg[bd][0], tw);
            }
            __builtin_amdgcn_s_setprio(1);
            if (k == 0) {
                // activation: K state, boundary, S-lag state, prefetch seeds
                RpK[0] = RpK[1] = BIGS; RpS[0] = RpS[1] = 1.0f;
                poK = (bd == 0 && t == 0) ? 0.0f : BIGS;
                poS_s = 1.0f;
                const float2 r0 = rKS[0];
                bnK = r0.x;          // unK(0): lane0 real, rest masked
                bnS = 1.0f;          // slot0's poS_s := bnS must be 1
                sprevS_d = r0.y;     // slot0's dppS old -> lane0 unS(0)
                smv[0] = rKS[1];     // sprev for slot 0 (seam col 1)
                smv[1] = rKS[2];     // sprev for slot 1 (seam col 2)
                rv[0] = rg[((unsigned)(0 - t)) & 127];   // col 0-t (tick 0)
                rv[1] = rg[((unsigned)(1 - t)) & 127];   // col 1-t (tick 1)
                SS_BODY(0)
            } else if (k >= 4 && k <= 31) {
                SS_BODY(1)
            } else {
                SS_BODY(0)
            }
            __builtin_amdgcn_s_setprio(0);
            asm volatile("s_waitcnt lgkmcnt(0)" ::: "memory");  // drain seam
            if (t == 0) *(volatile int*)&dpProg[bd] = tb + 16;
        }
    } else {
        // ================= producer wave: 32 tiles, free-running ===========
        int cDp = 0;
#pragma unroll 1
        for (int T = 0; T < 32; ++T) {
            if (T >= 4) {
                const int tgt = (T << 4) - 48;      // ring overwrite safety
                if (cDp < tgt) cDp = waitge(&dpProg[bd], tgt);
            }
            PRODUCE(T)
            asm volatile("s_waitcnt lgkmcnt(0)" ::: "memory");
            if (t == 0) *(volatile int*)&prodProg[bd][hf] = T + 1;
        }
    }
#undef LTICK
#undef RENORM
#undef SS_BODY
#undef PRODUCE

    // band 3, lane 63: K1(574) retained through masked slot 575; s1(574)
    // flushed at slot 575; RENORM kept the pair consistent.
    if (wv == 3 && t == 63) {
        atomicAdd(out, wgt * (RpK[1] - log2f(RpS[1])) * LN2F);
    }
}

__global__ void k_zero(float* out) {
    if (threadIdx.x == 0) out[0] = 0.0f;
}

extern "C" void kernel_launch(void* const* d_in, const int* in_sizes, int n_in,
                              void* d_out, int out_size, void* d_ws, size_t ws_size,
                              hipStream_t stream) {
    const float* X = (const float*)d_in[0];   // (64, 512, 16) f32
    const float* w = (const float*)d_in[1];   // (64,) f32
    const float* Z = (const float*)d_in[2];   // (512, 16) f32
    float* out = (float*)d_out;               // scalar f32

    hipLaunchKernelGGL(k_zero, dim3(1), dim3(64), 0, stream, out);
    hipLaunchKernelGGL(k_fused, dim3(64), dim3(768), 0, stream, X, Z, w, out);
}

// Round 13
// 162.166 us; speedup vs baseline: 1.0352x; 1.0163x over previous
//
#include <hip/hip_runtime.h>

#define TT 512
#define BIGS 1.4426950408889634e10f   // BIG(1e10) * log2(e), scaled domain
#define LOG2E 1.4426950408889634f
#define M2L  (-2.0f * 1.4426950408889634f)
#define LN2F 0.69314718055994531f
#define RSTR 130                      // ring row stride (words); 128 slots + pad

typedef _Float16 h2 __attribute__((ext_vector_type(2)));

__device__ __forceinline__ unsigned pk(float a, float b) {
    h2 v; v.x = (_Float16)a; v.y = (_Float16)b;
    return __builtin_bit_cast(unsigned, v);
}

#if __has_builtin(__builtin_amdgcn_fdot2)
#define FDOT2(a, b, c) __builtin_amdgcn_fdot2(__builtin_bit_cast(h2, (a)), \
                                              __builtin_bit_cast(h2, (b)), (c), false)
#else
__device__ __forceinline__ float fdot2_sw(unsigned a, unsigned b, float c) {
    h2 ha = __builtin_bit_cast(h2, a), hb = __builtin_bit_cast(h2, b);
    return c + (float)ha.x * (float)hb.x + (float)ha.y * (float)hb.y;
}
#define FDOT2(a, b, c) fdot2_sw((a), (b), (c))
#endif

#if __has_builtin(__builtin_amdgcn_exp2f)
#define EXP2F(x) __builtin_amdgcn_exp2f(x)
#else
#define EXP2F(x) exp2f(x)
#endif

// permuted Z index, pure bitops (valid for any int j; wraps out-of-range j
// onto some valid row -- garbage rows only feed masked ticks)
#define ZROW(jv) (((((jv) & 1)) << 8) | ((((jv) >> 1)) & 255))

// lane-shift-up-by-1 via DPP wave_shr:1 (VALU) on the loop-carried path.
// Lane 0 takes `old` = seam value. Verified r13-r21.
__device__ __forceinline__ float dppshr1(float x, float old) {
#if __has_builtin(__builtin_amdgcn_update_dpp)
    return __builtin_bit_cast(float,
        __builtin_amdgcn_update_dpp(__builtin_bit_cast(int, old),
                                    __builtin_bit_cast(int, x),
                                    0x138 /*wave_shr:1*/, 0xF, 0xF, false));
#else
    const float v = __shfl_up(x, 1);
    return ((threadIdx.x & 63) == 0) ? old : v;
#endif
}

// wave-uniform spin-wait on an LDS progress counter; returns last seen value
// so callers can cache it (flags are monotone -> cached >= target skips the
// ~120cy LDS poll round-trip entirely).
__device__ __forceinline__ int waitge(const volatile int* p, int v) {
    int x = *p;
    while (x < v) { __builtin_amdgcn_s_sleep(2); x = *p; }
    asm volatile("" ::: "memory");   // keep data reads below the wait
    return x;
}
__device__ __forceinline__ int waitge2(const volatile int* p, int v) {
    int a = p[0], b = p[1];
    while (a < v || b < v) { __builtin_amdgcn_s_sleep(2); a = p[0]; b = p[1]; }
    asm volatile("" ::: "memory");
    return (a < b) ? a : b;
}

// ---------------------------------------------------------------------------
// Round 23 = r21 RESTORED (r22's lag-2 was based on a wrong proof: the seam
// writer is LANE 63, so col c is written at slot c+64, not c+1 -- consumer
// truly needs prog >= tb+83; 6-batch lag is intrinsic to the band split).
// Only change vs r21: dpProg published TWICE per batch (8-slot grid), which
// legally tightens the forward gate from tb+96 (16-grid roundup of 83) to
// tb+88 (8-grid roundup): critical path 864 -> 840 slots (-2.8%).
// Hazards re-proved under the 8-grid:
//  * forward: gate tb+88 -> seam cols <= tb+23 written vs <= tb+18 read
//    (distance-3 prefetch), margin 5; publish value tb+8 after slots
//    tb..tb+7 == exactly "col c done iff prog >= c+65".
//  * anti-dep (seam-ring overwrite): gate k>=8, dpProg[bd+1] >= tb-112
//    unchanged -> writer-ahead <= 127 slots < 131 alias distance, margin 4.
//  * producer dd-ring gate 16T-48 unchanged (margin 3; prog semantics same).
//  * deadlock-free: blocked cycle implies prog <= 16k'-88 while anti needs
//    only >= 16k'-112 -> always satisfiable.
// Slot math (S-lag), renorm, masks, activation: byte-identical to r21
// (absmax 0 verified at 111.6us).
// ---------------------------------------------------------------------------
__global__ __launch_bounds__(768, 1) void k_fused(const float* __restrict__ X,
                                                  const float* __restrict__ Z,
                                                  const float* __restrict__ w,
                                                  float* __restrict__ out) {
    const int tt = threadIdx.x;
    const int t  = tt & 63;          // lane
    const int wv = tt >> 6;          // wave 0..11
    const int bd = wv & 3;           // band this wave serves
    const int hf = (wv >= 8) ? 1 : 0;// producer half (wv>=4 only)
    const int n  = blockIdx.x;       // sample

    __shared__ uint4    ZA[2][512];  // Z rows fp16-packed, permuted idx
    __shared__ float    Zs2p[512];   // LOG2E*|z|^2 at permuted idx
    __shared__ float2   seam[4][64]; // seam rings (K, sm); band0 = border
    __shared__ unsigned ring[4][64][RSTR];  // fp16x2 dd pairs, slot = col&127
    __shared__ int      dpProg[4];   // DP progress (local slots done)
    __shared__ int      prodProg[4][2];  // producer progress (tiles done)

    // ---- stage Z into LDS: threads 0..511 handle one row each ----
    if (tt < 512) {
        const int r = tt;
        const float4* zp = (const float4*)(Z + (size_t)r * 16);
        const float4 a0 = zp[0], a1 = zp[1], a2 = zp[2], a3 = zp[3];
        float sv = 0.0f;
        sv = fmaf(a0.x, a0.x, sv); sv = fmaf(a0.y, a0.y, sv);
        sv = fmaf(a0.z, a0.z, sv); sv = fmaf(a0.w, a0.w, sv);
        sv = fmaf(a1.x, a1.x, sv); sv = fmaf(a1.y, a1.y, sv);
        sv = fmaf(a1.z, a1.z, sv); sv = fmaf(a1.w, a1.w, sv);
        sv = fmaf(a2.x, a2.x, sv); sv = fmaf(a2.y, a2.y, sv);
        sv = fmaf(a2.z, a2.z, sv); sv = fmaf(a2.w, a2.w, sv);
        sv = fmaf(a3.x, a3.x, sv); sv = fmaf(a3.y, a3.y, sv);
        sv = fmaf(a3.z, a3.z, sv); sv = fmaf(a3.w, a3.w, sv);
        const int idx = ((r & 1) << 8) | (r >> 1);
        ZA[0][idx] = make_uint4(pk(a0.x, a0.y), pk(a0.z, a0.w),
                                pk(a1.x, a1.y), pk(a1.z, a1.w));
        ZA[1][idx] = make_uint4(pk(a2.x, a2.y), pk(a2.z, a2.w),
                                pk(a3.x, a3.y), pk(a3.z, a3.w));
        Zs2p[idx] = LOG2E * sv;
    }
    // seam rings -> (BIGS, 1): matrix border; band-0 ring never written.
    if (tt < 256) ((float2*)&seam[0][0])[tt] = make_float2(BIGS, 1.0f);
    // progress flags
    if (tt < 4) dpProg[tt] = 0;
    if (tt < 8) (&prodProg[0][0])[tt] = 0;

    // ---- X rows for band bd, lane t (rows i0, i0+1) -> registers ----
    const int i0 = 128 * bd + 2 * t;
    unsigned Xu[2][8];
    float    xs2[2];
    const float* xp = X + ((size_t)n * TT + i0) * 16;
#pragma unroll
    for (int q = 0; q < 2; ++q) {
        const float4* xr = (const float4*)(xp + q * 16);
        const float4 a0 = xr[0], a1 = xr[1], a2 = xr[2], a3 = xr[3];
        float sv = 0.0f;
        sv = fmaf(a0.x, a0.x, sv); sv = fmaf(a0.y, a0.y, sv);
        sv = fmaf(a0.z, a0.z, sv); sv = fmaf(a0.w, a0.w, sv);
        sv = fmaf(a1.x, a1.x, sv); sv = fmaf(a1.y, a1.y, sv);
        sv = fmaf(a1.z, a1.z, sv); sv = fmaf(a1.w, a1.w, sv);
        sv = fmaf(a2.x, a2.x, sv); sv = fmaf(a2.y, a2.y, sv);
        sv = fmaf(a2.z, a2.z, sv); sv = fmaf(a2.w, a2.w, sv);
        sv = fmaf(a3.x, a3.x, sv); sv = fmaf(a3.y, a3.y, sv);
        sv = fmaf(a3.z, a3.z, sv); sv = fmaf(a3.w, a3.w, sv);
        xs2[q] = LOG2E * sv;
        Xu[q][0] = pk(a0.x, a0.y); Xu[q][1] = pk(a0.z, a0.w);
        Xu[q][2] = pk(a1.x, a1.y); Xu[q][3] = pk(a1.z, a1.w);
        Xu[q][4] = pk(a2.x, a2.y); Xu[q][5] = pk(a2.z, a2.w);
        Xu[q][6] = pk(a3.x, a3.y); Xu[q][7] = pk(a3.z, a3.w);
    }
    const float wgt = w[n];
    const float2* rKS = &seam[bd][0];
    unsigned* const rg = &ring[bd][t][0];
    __syncthreads();   // the ONLY barrier: staging + flag init

    // producer: fp16-packed dd pair for 8 cols of tile Tv (half hf)
#define PRODUCE(Tv)                                                           \
    {                                                                         \
        const int base_ = ((Tv) << 4) + (hf << 3);                            \
        const int wb_ = base_ & 127;                                          \
        _Pragma("unroll 4")                                                   \
        for (int cc = 0; cc < 8; ++cc) {                                      \
            const int zr = ZROW(base_ + cc);       /* wave-uniform */         \
            const uint4 z0 = ZA[0][zr], z1 = ZA[1][zr];                       \
            const float zz = Zs2p[zr];                                        \
            float a0 = 0.0f, b0 = 0.0f, a1 = 0.0f, b1 = 0.0f;                 \
            a0 = FDOT2(z0.x, Xu[0][0], a0); a0 = FDOT2(z0.y, Xu[0][1], a0);   \
            a0 = FDOT2(z0.z, Xu[0][2], a0); a0 = FDOT2(z0.w, Xu[0][3], a0);   \
            b0 = FDOT2(z1.x, Xu[0][4], b0); b0 = FDOT2(z1.y, Xu[0][5], b0);   \
            b0 = FDOT2(z1.z, Xu[0][6], b0); b0 = FDOT2(z1.w, Xu[0][7], b0);   \
            a1 = FDOT2(z0.x, Xu[1][0], a1); a1 = FDOT2(z0.y, Xu[1][1], a1);   \
            a1 = FDOT2(z0.z, Xu[1][2], a1); a1 = FDOT2(z0.w, Xu[1][3], a1);   \
            b1 = FDOT2(z1.x, Xu[1][4], b1); b1 = FDOT2(z1.y, Xu[1][5], b1);   \
            b1 = FDOT2(z1.z, Xu[1][6], b1); b1 = FDOT2(z1.w, Xu[1][7], b1);   \
            const float dd0 = fmaf(M2L, a0 + b0, xs2[0] + zz);                \
            const float dd1 = fmaf(M2L, a1 + b1, xs2[1] + zz);                \
            rg[wb_ + cc] = pk(dd0, dd1);                                      \
        }                                                                     \
    }

    // ---- DP state ----
    float RpK[2], RpS[2], poK, poS_s, bnK, bnS;
    float E[2][6];                   // exp ping-pong (written slot tl, read tl+1)
    float2 smv[2];                   // seam prefetch (distance 3, parity of tl)
    float sprevS_d;                  // seam .y delayed one slot (for dppS)
    unsigned rv[2];                  // ring prefetch slots (parity of tl)
    RpK[0] = RpK[1] = BIGS; RpS[0] = RpS[1] = 1.0f;
    poK = BIGS; poS_s = 1.0f; bnK = BIGS; bnS = 1.0f;
    sprevS_d = 1.0f;
    smv[0] = smv[1] = make_float2(BIGS, 1.0f);
    rv[0] = rv[1] = 0u;
#pragma unroll
    for (int e = 0; e < 6; ++e) { E[0][e] = 1.0f; E[1][e] = 1.0f; }

// q must equal (tl)&1 at each expansion (tb is even). ALLOK: compile-time
// "every lane valid for both tick tl and deferred tick tl-1".
#define LTICK(q, tl, ALLOK)                                                   \
    {                                                                         \
        const float K1_d = RpK[1];          /* K1(tl-1) for deferred seam */  \
        const float2 sprev = smv[q];        /* seam col tl+1 (prefetched) */  \
        smv[q] = rKS[((tl) + 3) & 63];      /* seam col tl+3, for slot tl+2 */\
        const h2 dh = __builtin_bit_cast(h2, rv[q]);                          \
        rv[q] = rg[((unsigned)((tl) + 2 - t)) & 127];  /* for tick tl+2 */    \
        const float dd0 = (float)dh.x, dd1 = (float)dh.y;                     \
        /* ---- K-chain, tick tl (no exp on the carried path) ---- */         \
        const float unK = bnK;                                                \
        const float pK  = poK;                                                \
        const float l0K = RpK[0], l1K = RpK[1];                               \
        const float m0 = fminf(fminf(unK, l0K), pK);                          \
        const float K0 = dd0 + m0;                                            \
        const float m1 = fminf(fminf(K0, l1K), l0K);                          \
        const float K1 = dd1 + m1;                                            \
        const bool okK = (ALLOK) ? true                                       \
                       : ((((tl) - t) >= 0) && (((tl) - t) < 512));           \
        RpK[0] = okK ? K0 : RpK[0];                                           \
        RpK[1] = okK ? K1 : RpK[1];                                           \
        poK = unK;                                                            \
        /* ---- exps for tick tl -> E[q], consumed NEXT slot ---- */          \
        E[q][0] = EXP2F(m0 - unK);                                            \
        E[q][1] = EXP2F(m0 - l0K);                                            \
        E[q][2] = EXP2F(m0 - pK);                                             \
        E[q][3] = EXP2F(m1 - K0);                                             \
        E[q][4] = EXP2F(m1 - l1K);                                            \
        E[q][5] = EXP2F(m1 - l0K);                                            \
        /* ---- deferred S-tree, tick tl-1 (E[q^1] issued last slot) ---- */  \
        const bool okS = (ALLOK) ? true                                       \
                       : ((((tl) - 1 - t) >= 0) && (((tl) - 1 - t) < 512));   \
        const float s0 = E[(q) ^ 1][0] * bnS + E[(q) ^ 1][1] * RpS[0]         \
                       + E[(q) ^ 1][2] * poS_s;                               \
        const float s1 = E[(q) ^ 1][3] * s0 + E[(q) ^ 1][4] * RpS[1]          \
                       + E[(q) ^ 1][5] * RpS[0];                              \
        RpS[0] = okS ? s0 : RpS[0];                                           \
        RpS[1] = okS ? s1 : RpS[1];                                           \
        if (okS && bd < 3 && t == 63) {   /* seam for tick tl-1; idx (tl)&63 */\
            seam[bd + 1][(tl) & 63] = make_float2(K1_d, RpS[1]);              \
        }                                                                     \
        poS_s = bnS;                        /* unS(tl-1) -> poS(tl) */        \
        /* ---- boundary DPPs ---- */                                         \
        bnK = dppshr1(RpK[1], sprev.x);     /* un K for tick tl+1 */          \
        bnS = dppshr1(RpS[1], sprevS_d);    /* un S for tick tl   */          \
        sprevS_d = sprev.y;                                                   \
    }

#define RENORM                                                                \
    {                                                                         \
        _Pragma("unroll")                                                     \
        for (int q = 0; q < 2; ++q) {                                         \
            const int e = (int)(__float_as_uint(RpS[q]) >> 23) - 127;         \
            RpS[q] = __uint_as_float(__float_as_uint(RpS[q])                  \
                                     - ((unsigned)e << 23));                  \
            RpK[q] -= (float)e;                                               \
        }                                                                     \
    }

#define SS_H1(A)                                                              \
    LTICK(0, tb + 0, A)  LTICK(1, tb + 1, A)  LTICK(0, tb + 2, A)             \
    LTICK(1, tb + 3, A)  LTICK(0, tb + 4, A)  LTICK(1, tb + 5, A)             \
    LTICK(0, tb + 6, A)  LTICK(1, tb + 7, A)                                  \
    RENORM

#define SS_H2(A)                                                              \
    LTICK(0, tb + 8, A)  LTICK(1, tb + 9, A)  LTICK(0, tb + 10, A)            \
    LTICK(1, tb + 11, A) LTICK(0, tb + 12, A) LTICK(1, tb + 13, A)            \
    LTICK(0, tb + 14, A) LTICK(1, tb + 15, A)                                 \
    RENORM

// batch body with mid-batch publish (8-slot progress grid)
#define RUN_BATCH(A)                                                          \
    SS_H1(A)                                                                  \
    asm volatile("s_waitcnt lgkmcnt(0)" ::: "memory");                        \
    if (t == 0) *(volatile int*)&dpProg[bd] = tb + 8;                         \
    SS_H2(A)

    if (wv < 4) {
        // ================= DP wave: 36 batches of 16 slots =================
        int cSeam = 0, cOvw = 0, cProd = 0;   // cached flag values
#pragma unroll 1
        for (int k = 0; k < 36; ++k) {
            const int tb = k << 4;
            if (bd > 0) {
                // forward gate on 8-grid: need prog >= tb+83 -> tb+88
                const int tgt = (tb + 88 < 576) ? tb + 88 : 576;
                if (cSeam < tgt) cSeam = waitge(&dpProg[bd - 1], tgt);
            }
            if (bd < 3 && k >= 8) {
                // seam-ring overwrite back-pressure (unchanged from r21)
                const int tgt = tb - 112;
                if (cOvw < tgt) cOvw = waitge(&dpProg[bd + 1], tgt);
            }
            {
                const int tw = (k + 2 < 32) ? k + 2 : 32;
                if (cProd < tw) cProd = waitge2(&prodProg[bd][0], tw);
            }
            __builtin_amdgcn_s_setprio(1);
            if (k == 0) {
                // activation: K state, boundary, S-lag state, prefetch seeds
                RpK[0] = RpK[1] = BIGS; RpS[0] = RpS[1] = 1.0f;
                poK = (bd == 0 && t == 0) ? 0.0f : BIGS;
                poS_s = 1.0f;
                const float2 r0 = rKS[0];
                bnK = r0.x;          // unK(0): lane0 real, rest masked
                bnS = 1.0f;          // slot0's poS_s := bnS must be 1
                sprevS_d = r0.y;     // slot0's dppS old -> lane0 unS(0)
                smv[0] = rKS[1];     // sprev for slot 0 (seam col 1)
                smv[1] = rKS[2];     // sprev for slot 1 (seam col 2)
                rv[0] = rg[((unsigned)(0 - t)) & 127];   // col 0-t (tick 0)
                rv[1] = rg[((unsigned)(1 - t)) & 127];   // col 1-t (tick 1)
                RUN_BATCH(0)
            } else if (k >= 4 && k <= 31) {
                RUN_BATCH(1)
            } else {
                RUN_BATCH(0)
            }
            __builtin_amdgcn_s_setprio(0);
            asm volatile("s_waitcnt lgkmcnt(0)" ::: "memory");  // drain seam
            if (t == 0) *(volatile int*)&dpProg[bd] = tb + 16;
        }
    } else {
        // ================= producer wave: 32 tiles, free-running ===========
        int cDp = 0;
#pragma unroll 1
        for (int T = 0; T < 32; ++T) {
            if (T >= 4) {
                const int tgt = (T << 4) - 48;      // ring overwrite safety
                if (cDp < tgt) cDp = waitge(&dpProg[bd], tgt);
            }
            PRODUCE(T)
            asm volatile("s_waitcnt lgkmcnt(0)" ::: "memory");
            if (t == 0) *(volatile int*)&prodProg[bd][hf] = T + 1;
        }
    }
#undef LTICK
#undef RENORM
#undef SS_H1
#undef SS_H2
#undef RUN_BATCH
#undef PRODUCE

    // band 3, lane 63: K1(574) retained through masked slot 575; s1(574)
    // flushed at slot 575; RENORM kept the pair consistent.
    if (wv == 3 && t == 63) {
        atomicAdd(out, wgt * (RpK[1] - log2f(RpS[1])) * LN2F);
    }
}

__global__ void k_zero(float* out) {
    if (threadIdx.x == 0) out[0] = 0.0f;
}

extern "C" void kernel_launch(void* const* d_in, const int* in_sizes, int n_in,
                              void* d_out, int out_size, void* d_ws, size_t ws_size,
                              hipStream_t stream) {
    const float* X = (const float*)d_in[0];   // (64, 512, 16) f32
    const float* w = (const float*)d_in[1];   // (64,) f32
    const float* Z = (const float*)d_in[2];   // (512, 16) f32
    float* out = (float*)d_out;               // scalar f32

    hipLaunchKernelGGL(k_zero, dim3(1), dim3(64), 0, stream, out);
    hipLaunchKernelGGL(k_fused, dim3(64), dim3(768), 0, stream, X, Z, w, out);
}